// Round 2
// baseline (357.203 us; speedup 1.0000x reference)
//
#include <hip/hip_runtime.h>

#define B 16
#define E 1024
#define T 1025     // tokens incl. mean token
#define SP 1024    // spatial tokens
#define H 16
#define CH 64

__inline__ __device__ float blockReduceSum(float v, float* sm) {
    int tid = threadIdx.x;
    sm[tid] = v; __syncthreads();
    for (int s = 128; s > 0; s >>= 1) {
        if (tid < s) sm[tid] += sm[tid + s];
        __syncthreads();
    }
    float r = sm[0]; __syncthreads();
    return r;
}

__inline__ __device__ float blockReduceMax(float v, float* sm) {
    int tid = threadIdx.x;
    sm[tid] = v; __syncthreads();
    for (int s = 128; s > 0; s >>= 1) {
        if (tid < s) sm[tid] = fmaxf(sm[tid], sm[tid + s]);
        __syncthreads();
    }
    float r = sm[0]; __syncthreads();
    return r;
}

// K0: posA[e][t] = pos[e][t+1]  (16B-aligned repack of spatial pos columns)
__global__ void k_posA(const float* __restrict__ pos, float* __restrict__ posA) {
    int e = blockIdx.x;
    int t = threadIdx.x * 4;
    const float* s = pos + (size_t)e * T + 1 + t;
    float4 v;
    v.x = s[0]; v.y = s[1]; v.z = s[2]; v.w = s[3];
    *(float4*)(posA + (size_t)e * SP + t) = v;
}

// K1: x0[b,e] = mean_t x[b,e,t] + pos_emb[e,0]
__global__ void k_mean_x0(const float* __restrict__ x, const float* __restrict__ pos,
                          float* __restrict__ x0) {
    int row = blockIdx.x;          // b*E + e
    int e = row & (E - 1);
    const float4* x4 = (const float4*)(x + (size_t)row * SP);
    float4 v = x4[threadIdx.x];
    float s = v.x + v.y + v.z + v.w;
    __shared__ float sm[256];
    float tot = blockReduceSum(s, sm);
    if (threadIdx.x == 0)
        x0[row] = tot * (1.0f / SP) + pos[(size_t)e * T];
}

// K2: q0[b,o] = W_q[o,:]·x0[b,:] + b_q[o]
__global__ void k_q0(const float* __restrict__ wqkv, const float* __restrict__ bqkv,
                     const float* __restrict__ x0, float* __restrict__ q0) {
    int o = blockIdx.x, b = blockIdx.y;
    const float4* w4 = (const float4*)(wqkv + (size_t)o * E);
    const float4* x4 = (const float4*)(x0 + (size_t)b * E);
    float4 w = w4[threadIdx.x], xv = x4[threadIdx.x];
    float s = w.x * xv.x + w.y * xv.y + w.z * xv.z + w.w * xv.w;
    __shared__ float sm[256];
    float tot = blockReduceSum(s, sm);
    if (threadIdx.x == 0) q0[b * E + o] = tot + bqkv[o];
}

// K3: u[b,h,e] = 0.125 * sum_c q0[b,h*64+c] * W_k[h*64+c, e]
__global__ void k_u(const float* __restrict__ wqkv, const float* __restrict__ q0,
                    float* __restrict__ u) {
    int h = blockIdx.x, b = blockIdx.y;
    __shared__ float qs[CH];
    if (threadIdx.x < CH) qs[threadIdx.x] = q0[b * E + h * CH + threadIdx.x];
    __syncthreads();
    float acc[4] = {0.f, 0.f, 0.f, 0.f};
    for (int c = 0; c < CH; ++c) {
        float qv = qs[c];
        const float* wr = wqkv + (size_t)(E + h * CH + c) * E;
        #pragma unroll
        for (int j = 0; j < 4; ++j)
            acc[j] += qv * wr[j * 256 + threadIdx.x];
    }
    float* ur = u + (size_t)(b * H + h) * E;
    #pragma unroll
    for (int j = 0; j < 4; ++j) ur[j * 256 + threadIdx.x] = 0.125f * acc[j];
}

// K4: sc[b,h,t] += sum_{e in chunk} u[b,h,e]*(x[b,e,t] + posA[e,t]),  t = 0..1023
// thread <-> t-quad (float4); e-chunk of 32 per block; acc[16] float4 in regs.
__global__ void __launch_bounds__(256, 2) k_scores(
        const float* __restrict__ x, const float* __restrict__ posA,
        const float* __restrict__ u, float* __restrict__ sc) {
    int ec = blockIdx.x;   // 0..31  (32 e per chunk)
    int b  = blockIdx.y;
    int tid = threadIdx.x;
    int e0 = ec * 32;
    __shared__ float us[H][32];
    for (int i = tid; i < H * 32; i += 256) {
        int h = i >> 5, el = i & 31;
        us[h][el] = u[(size_t)(b * H + h) * E + e0 + el];
    }
    __syncthreads();
    float4 acc[H];
    #pragma unroll
    for (int h = 0; h < H; ++h) acc[h] = make_float4(0.f, 0.f, 0.f, 0.f);
    for (int eq = 0; eq < 8; ++eq) {
        float4 val[4];
        #pragma unroll
        for (int j = 0; j < 4; ++j) {
            int e = e0 + eq * 4 + j;
            float4 xv = *(const float4*)(x + ((size_t)(b * E + e)) * SP + 4 * tid);
            float4 pv = *(const float4*)(posA + (size_t)e * SP + 4 * tid);
            val[j] = make_float4(xv.x + pv.x, xv.y + pv.y, xv.z + pv.z, xv.w + pv.w);
        }
        #pragma unroll
        for (int h = 0; h < H; ++h) {
            float4 uu = *(const float4*)&us[h][eq * 4];
            acc[h].x += uu.x * val[0].x + uu.y * val[1].x + uu.z * val[2].x + uu.w * val[3].x;
            acc[h].y += uu.x * val[0].y + uu.y * val[1].y + uu.z * val[2].y + uu.w * val[3].y;
            acc[h].z += uu.x * val[0].z + uu.y * val[1].z + uu.z * val[2].z + uu.w * val[3].z;
            acc[h].w += uu.x * val[0].w + uu.y * val[1].w + uu.z * val[2].w + uu.w * val[3].w;
        }
    }
    #pragma unroll
    for (int h = 0; h < H; ++h) {
        float* scr = sc + ((size_t)(b * H + h)) * SP + 4 * tid;
        atomicAdd(&scr[0], acc[h].x);
        atomicAdd(&scr[1], acc[h].y);
        atomicAdd(&scr[2], acc[h].z);
        atomicAdd(&scr[3], acc[h].w);
    }
}

// K5: per (b,h): s0 = u·x0; softmax over [s0, sc[0..1023]] -> p0, p[0..1023];
//     also y-init: y[b,h,e] = p0 * x0[b,e]
__global__ void k_softmax(const float* __restrict__ u, const float* __restrict__ x0,
                          const float* __restrict__ sc, float* __restrict__ p,
                          float* __restrict__ p0, float* __restrict__ y) {
    int bh = blockIdx.x;
    int b = bh >> 4;
    int tid = threadIdx.x;
    __shared__ float sm[256];
    const float4* u4 = (const float4*)(u + (size_t)bh * E);
    const float4* x4 = (const float4*)(x0 + (size_t)b * E);
    float4 uv = u4[tid], xv = x4[tid];
    float d = uv.x * xv.x + uv.y * xv.y + uv.z * xv.z + uv.w * xv.w;
    float s0 = blockReduceSum(d, sm);
    float4 v = ((const float4*)(sc + (size_t)bh * SP))[tid];
    float mx = fmaxf(fmaxf(v.x, v.y), fmaxf(v.z, v.w));
    mx = fmaxf(mx, s0);
    mx = blockReduceMax(mx, sm);
    v.x = expf(v.x - mx); v.y = expf(v.y - mx);
    v.z = expf(v.z - mx); v.w = expf(v.w - mx);
    float es0 = expf(s0 - mx);
    float sum = v.x + v.y + v.z + v.w + (tid == 0 ? es0 : 0.f);
    sum = blockReduceSum(sum, sm);
    float inv = 1.0f / sum;
    ((float4*)(p + (size_t)bh * SP))[tid] =
        make_float4(v.x * inv, v.y * inv, v.z * inv, v.w * inv);
    float p0v = es0 * inv;
    if (tid == 0) p0[bh] = p0v;
    ((float4*)(y + (size_t)bh * E))[tid] =
        make_float4(p0v * xv.x, p0v * xv.y, p0v * xv.z, p0v * xv.w);
}

// K6: y[b,h,e] += sum_t p[b,h,t]*(x[b,e,t] + posA[e,t])
// thread <-> (8h x 8e) output tile; LDS holds x+pos TRANSPOSED xs[t][e] so
// compute reads are canonical consecutive-lane ds_read_b128 (conflict-free).
#define YTC 16          // t per staged chunk
#define YLP 1028        // padded e-stride (breaks 4-way store conflicts, keeps 16B align)

__global__ void __launch_bounds__(256, 2) k_y(
        const float* __restrict__ x, const float* __restrict__ posA,
        const float* __restrict__ p, float* __restrict__ y) {
    int tb = blockIdx.x;          // 0..31 : t-range of 32
    int b  = blockIdx.y;
    int tid = threadIdx.x;
    int hg = tid >> 7;            // 0..1   -> h = 8*hg + j
    int eg = tid & 127;           // 0..127 -> e in {4eg..4eg+3} U {512+4eg..}
    __shared__ float xs[YTC][YLP];
    __shared__ float ps[YTC][16];
    float acc[8][8];
    #pragma unroll
    for (int j = 0; j < 8; ++j)
        #pragma unroll
        for (int i = 0; i < 8; ++i) acc[j][i] = 0.f;

    for (int ch = 0; ch < 2; ++ch) {
        int t0 = tb * 32 + ch * YTC;
        __syncthreads();
        // stage xs[t][e] = x + posA for 1024 e x 16 t  (16 float4 per thread)
        #pragma unroll
        for (int it = 0; it < 16; ++it) {
            int f4id = it * 256 + tid;
            int e  = f4id >> 2;
            int c4 = (f4id & 3) * 4;
            float4 xv = *(const float4*)(x + ((size_t)(b * E + e)) * SP + t0 + c4);
            float4 pv = *(const float4*)(posA + (size_t)e * SP + t0 + c4);
            xs[c4 + 0][e] = xv.x + pv.x;
            xs[c4 + 1][e] = xv.y + pv.y;
            xs[c4 + 2][e] = xv.z + pv.z;
            xs[c4 + 3][e] = xv.w + pv.w;
        }
        if (tid < 64) {
            int hh = tid & 15, c4 = (tid >> 4) * 4;
            float4 pv = *(const float4*)(p + ((size_t)(b * H + hh)) * SP + t0 + c4);
            ps[c4 + 0][hh] = pv.x;
            ps[c4 + 1][hh] = pv.y;
            ps[c4 + 2][hh] = pv.z;
            ps[c4 + 3][hh] = pv.w;
        }
        __syncthreads();
        #pragma unroll 4
        for (int c = 0; c < YTC; ++c) {
            float4 xa = *(const float4*)&xs[c][4 * eg];
            float4 xb = *(const float4*)&xs[c][512 + 4 * eg];
            float4 pa = *(const float4*)&ps[c][8 * hg];
            float4 pb = *(const float4*)&ps[c][8 * hg + 4];
            float xch[8] = {xa.x, xa.y, xa.z, xa.w, xb.x, xb.y, xb.z, xb.w};
            float pch[8] = {pa.x, pa.y, pa.z, pa.w, pb.x, pb.y, pb.z, pb.w};
            #pragma unroll
            for (int j = 0; j < 8; ++j)
                #pragma unroll
                for (int i = 0; i < 8; ++i)
                    acc[j][i] += pch[j] * xch[i];
        }
    }
    #pragma unroll
    for (int j = 0; j < 8; ++j) {
        float* yr = y + ((size_t)(b * H + 8 * hg + j)) * E;
        #pragma unroll
        for (int i = 0; i < 4; ++i) atomicAdd(&yr[4 * eg + i], acc[j][i]);
        #pragma unroll
        for (int i = 0; i < 4; ++i) atomicAdd(&yr[512 + 4 * eg + i], acc[j][i + 4]);
    }
}

// K7: a[b,c] = W_v[c,:]·y[b,h(c),:] + b_v[c]
__global__ void k_a(const float* __restrict__ wqkv, const float* __restrict__ bqkv,
                    const float* __restrict__ y, float* __restrict__ a) {
    int c = blockIdx.x, b = blockIdx.y;
    int h = c >> 6;
    const float4* w4 = (const float4*)(wqkv + (size_t)(2 * E + c) * E);
    const float4* y4 = (const float4*)(y + (size_t)(b * H + h) * E);
    float4 w = w4[threadIdx.x], yv = y4[threadIdx.x];
    float s = w.x * yv.x + w.y * yv.y + w.z * yv.z + w.w * yv.w;
    __shared__ float sm[256];
    float tot = blockReduceSum(s, sm);
    if (threadIdx.x == 0) a[b * E + c] = tot + bqkv[2 * E + c];
}

// K8: out[b,o] = W_c[o,:]·a[b,:] + b_c[o]
__global__ void k_out(const float* __restrict__ wc, const float* __restrict__ bc,
                      const float* __restrict__ a, float* __restrict__ out) {
    int o = blockIdx.x, b = blockIdx.y;
    const float4* w4 = (const float4*)(wc + (size_t)o * E);
    const float4* a4 = (const float4*)(a + (size_t)b * E);
    float4 w = w4[threadIdx.x], av = a4[threadIdx.x];
    float s = w.x * av.x + w.y * av.y + w.z * av.z + w.w * av.w;
    __shared__ float sm[256];
    float tot = blockReduceSum(s, sm);
    if (threadIdx.x == 0) out[b * E + o] = tot + bc[o];
}

extern "C" void kernel_launch(void* const* d_in, const int* in_sizes, int n_in,
                              void* d_out, int out_size, void* d_ws, size_t ws_size,
                              hipStream_t stream) {
    const float* x    = (const float*)d_in[0];
    const float* pos  = (const float*)d_in[1];
    const float* wqkv = (const float*)d_in[2];
    const float* bqkv = (const float*)d_in[3];
    const float* wc   = (const float*)d_in[4];
    const float* bc   = (const float*)d_in[5];
    float* out = (float*)d_out;

    float* ws = (float*)d_ws;
    float* x0   = ws;                      // B*E
    float* q0   = x0 + B * E;              // B*E
    float* u    = q0 + B * E;              // B*H*E
    float* sc   = u + (size_t)B * H * E;   // B*H*SP
    float* p    = sc + (size_t)B * H * SP; // B*H*SP
    float* p0   = p + (size_t)B * H * SP;  // B*H
    float* y    = p0 + B * H;              // B*H*E
    float* a    = y + (size_t)B * H * E;   // B*E
    float* posA = a + B * E;               // E*SP

    hipMemsetAsync(sc, 0, (size_t)B * H * SP * sizeof(float), stream);

    k_posA<<<E, 256, 0, stream>>>(pos, posA);
    k_mean_x0<<<B * E, 256, 0, stream>>>(x, pos, x0);
    k_q0<<<dim3(E, B), 256, 0, stream>>>(wqkv, bqkv, x0, q0);
    k_u<<<dim3(H, B), 256, 0, stream>>>(wqkv, q0, u);
    k_scores<<<dim3(32, B), 256, 0, stream>>>(x, posA, u, sc);
    k_softmax<<<B * H, 256, 0, stream>>>(u, x0, sc, p, p0, y);
    k_y<<<dim3(32, B), 256, 0, stream>>>(x, posA, p, y);
    k_a<<<dim3(E, B), 256, 0, stream>>>(wqkv, bqkv, y, a);
    k_out<<<dim3(E, B), 256, 0, stream>>>(wc, bc, a, out);
}

// Round 3
// 134.043 us; speedup vs baseline: 2.6648x; 2.6648x over previous
//
#include <hip/hip_runtime.h>

#define B 16
#define E 1024
#define T 1025
#define SP 1024
#define H 16

__inline__ __device__ float blockReduceSum(float v, float* sm) {
    int tid = threadIdx.x;
    sm[tid] = v; __syncthreads();
    for (int s = 128; s > 0; s >>= 1) {
        if (tid < s) sm[tid] += sm[tid + s];
        __syncthreads();
    }
    float r = sm[0]; __syncthreads();
    return r;
}

__inline__ __device__ float blockReduceMax(float v, float* sm) {
    int tid = threadIdx.x;
    sm[tid] = v; __syncthreads();
    for (int s = 128; s > 0; s >>= 1) {
        if (tid < s) sm[tid] = fmaxf(sm[tid], sm[tid + s]);
        __syncthreads();
    }
    float r = sm[0]; __syncthreads();
    return r;
}

// multi-value butterfly: 16 values over 64 lanes, 17 shuffles total.
// Returns: lane l holds the full 64-lane sum of value (l & 15).
__device__ inline float reduce16x64(const float v[16], int lane) {
    float r8[8], r4[4], r2[2], r1;
    {
        int bit = lane & 1;
        #pragma unroll
        for (int j = 0; j < 8; ++j) {
            float mine  = bit ? v[2*j+1] : v[2*j];
            float other = bit ? v[2*j]   : v[2*j+1];
            r8[j] = mine + __shfl_xor(other, 1, 64);
        }
    }
    {
        int bit = (lane >> 1) & 1;
        #pragma unroll
        for (int j = 0; j < 4; ++j) {
            float mine  = bit ? r8[2*j+1] : r8[2*j];
            float other = bit ? r8[2*j]   : r8[2*j+1];
            r4[j] = mine + __shfl_xor(other, 2, 64);
        }
    }
    {
        int bit = (lane >> 2) & 1;
        #pragma unroll
        for (int j = 0; j < 2; ++j) {
            float mine  = bit ? r4[2*j+1] : r4[2*j];
            float other = bit ? r4[2*j]   : r4[2*j+1];
            r2[j] = mine + __shfl_xor(other, 4, 64);
        }
    }
    {
        int bit = (lane >> 3) & 1;
        float mine  = bit ? r2[1] : r2[0];
        float other = bit ? r2[0] : r2[1];
        r1 = mine + __shfl_xor(other, 8, 64);
    }
    r1 += __shfl_xor(r1, 16, 64);
    r1 += __shfl_xor(r1, 32, 64);
    return r1;
}

// K_pre: blocks [0,4096): mean rows (wave per row); blocks [4096,5120): posA repack
__global__ void k_pre(const float* __restrict__ x, const float* __restrict__ pos,
                      float* __restrict__ x0, float* __restrict__ posA) {
    int bid = blockIdx.x;
    int tid = threadIdx.x;
    if (bid < 4096) {
        int wave = tid >> 6, lane = tid & 63;
        int row = bid * 4 + wave;           // b*E + e
        int e = row & (E - 1);
        const float4* x4 = (const float4*)(x + (size_t)row * SP);
        float s = 0.f;
        #pragma unroll
        for (int it = 0; it < 4; ++it) {
            float4 v = x4[it * 64 + lane];
            s += v.x + v.y + v.z + v.w;
        }
        #pragma unroll
        for (int m = 1; m < 64; m <<= 1) s += __shfl_xor(s, m, 64);
        if (lane == 0) x0[row] = s * (1.0f / SP) + pos[(size_t)e * T];
    } else {
        int e = bid - 4096;
        int t = tid * 4;
        const float* src = pos + (size_t)e * T + 1 + t;
        float4 v;
        v.x = src[0]; v.y = src[1]; v.z = src[2]; v.w = src[3];
        *(float4*)(posA + (size_t)e * SP + t) = v;
    }
}

// K_q0: wave per output row o; 16 batch dots at once; butterfly reduce.
__global__ void k_q0(const float* __restrict__ wqkv, const float* __restrict__ bqkv,
                     const float* __restrict__ x0, float* __restrict__ q0) {
    int wave = threadIdx.x >> 6, lane = threadIdx.x & 63;
    int o = blockIdx.x * 4 + wave;
    const float* wrow = wqkv + (size_t)o * E;
    float acc[16];
    #pragma unroll
    for (int b = 0; b < 16; ++b) acc[b] = 0.f;
    #pragma unroll
    for (int it = 0; it < 4; ++it) {
        int e4 = (it * 64 + lane) * 4;
        float4 wv = *(const float4*)(wrow + e4);
        #pragma unroll
        for (int b = 0; b < 16; ++b) {
            float4 xv = *(const float4*)(x0 + (size_t)b * E + e4);
            acc[b] += wv.x * xv.x + wv.y * xv.y + wv.z * xv.z + wv.w * xv.w;
        }
    }
    float tot = reduce16x64(acc, lane);
    if (lane < 16) q0[lane * E + o] = tot + bqkv[o];
}

// K_u: u[b,h,e] = 0.125 * sum_c q0[b,h*64+c] * W_k[h*64+c, e]
__global__ void k_u(const float* __restrict__ wqkv, const float* __restrict__ q0,
                    float* __restrict__ u) {
    int h = blockIdx.x, b = blockIdx.y;
    int tid = threadIdx.x;
    __shared__ float qs[64];
    if (tid < 64) qs[tid] = q0[b * E + h * 64 + tid];
    __syncthreads();
    float4 acc = make_float4(0.f, 0.f, 0.f, 0.f);
    const float* wbase = wqkv + (size_t)(E + h * 64) * E + tid * 4;
    for (int c = 0; c < 64; ++c) {
        float4 wv = *(const float4*)(wbase + (size_t)c * E);
        float qv = qs[c];
        acc.x += qv * wv.x; acc.y += qv * wv.y;
        acc.z += qv * wv.z; acc.w += qv * wv.w;
    }
    float* ur = u + (size_t)(b * H + h) * E + tid * 4;
    *(float4*)ur = make_float4(0.125f * acc.x, 0.125f * acc.y,
                               0.125f * acc.z, 0.125f * acc.w);
}

// K_scores: sc_part[es][b*H+h][t] = sum_{e in chunk es} u[b,h,e]*(x[b,e,t]+posA[e,t])
__global__ void __launch_bounds__(256, 2) k_scores(
        const float* __restrict__ x, const float* __restrict__ posA,
        const float* __restrict__ u, float* __restrict__ sc_part) {
    int es = blockIdx.x;   // 0..15, e-chunk of 64
    int b  = blockIdx.y;
    int tid = threadIdx.x;
    int e0 = es * 64;
    int t4 = tid * 4;
    __shared__ float us[H][64];
    for (int i = tid; i < H * 64; i += 256) {
        int h = i >> 6, el = i & 63;
        us[h][el] = u[(size_t)(b * H + h) * E + e0 + el];
    }
    __syncthreads();
    float4 acc[H];
    #pragma unroll
    for (int h = 0; h < H; ++h) acc[h] = make_float4(0.f, 0.f, 0.f, 0.f);
    for (int eq = 0; eq < 16; ++eq) {
        float4 val[4];
        #pragma unroll
        for (int j = 0; j < 4; ++j) {
            int e = e0 + eq * 4 + j;
            float4 xv = *(const float4*)(x + ((size_t)(b * E + e)) * SP + t4);
            float4 pv = *(const float4*)(posA + (size_t)e * SP + t4);
            val[j] = make_float4(xv.x + pv.x, xv.y + pv.y, xv.z + pv.z, xv.w + pv.w);
        }
        #pragma unroll
        for (int h = 0; h < H; ++h) {
            float4 uu = *(const float4*)&us[h][eq * 4];
            acc[h].x += uu.x * val[0].x + uu.y * val[1].x + uu.z * val[2].x + uu.w * val[3].x;
            acc[h].y += uu.x * val[0].y + uu.y * val[1].y + uu.z * val[2].y + uu.w * val[3].y;
            acc[h].z += uu.x * val[0].z + uu.y * val[1].z + uu.z * val[2].z + uu.w * val[3].z;
            acc[h].w += uu.x * val[0].w + uu.y * val[1].w + uu.z * val[2].w + uu.w * val[3].w;
        }
    }
    #pragma unroll
    for (int h = 0; h < H; ++h)
        *(float4*)(sc_part + ((size_t)(es * 256) + b * H + h) * SP + t4) = acc[h];
}

// K_softmax: reduce 16 sc partials; s0 = u·x0; softmax -> pT[b][t][h], p0[bh]
__global__ void k_softmax(const float* __restrict__ u, const float* __restrict__ x0,
                          const float* __restrict__ sc_part, float* __restrict__ pT,
                          float* __restrict__ p0) {
    int bh = blockIdx.x;
    int b = bh >> 4, h = bh & 15;
    int tid = threadIdx.x;
    __shared__ float sm[256];
    float4 uv = ((const float4*)(u + (size_t)bh * E))[tid];
    float4 xv = ((const float4*)(x0 + (size_t)b * E))[tid];
    float d = uv.x * xv.x + uv.y * xv.y + uv.z * xv.z + uv.w * xv.w;
    float s0 = blockReduceSum(d, sm);
    float4 v = make_float4(0.f, 0.f, 0.f, 0.f);
    #pragma unroll
    for (int es = 0; es < 16; ++es) {
        float4 pv = ((const float4*)(sc_part + ((size_t)(es * 256) + bh) * SP))[tid];
        v.x += pv.x; v.y += pv.y; v.z += pv.z; v.w += pv.w;
    }
    float mx = fmaxf(fmaxf(v.x, v.y), fmaxf(v.z, v.w));
    mx = fmaxf(mx, s0);
    mx = blockReduceMax(mx, sm);
    v.x = expf(v.x - mx); v.y = expf(v.y - mx);
    v.z = expf(v.z - mx); v.w = expf(v.w - mx);
    float es0 = expf(s0 - mx);
    float sum = v.x + v.y + v.z + v.w + (tid == 0 ? es0 : 0.f);
    sum = blockReduceSum(sum, sm);
    float inv = 1.0f / sum;
    int t = tid * 4;
    pT[((size_t)b * SP + t + 0) * H + h] = v.x * inv;
    pT[((size_t)b * SP + t + 1) * H + h] = v.y * inv;
    pT[((size_t)b * SP + t + 2) * H + h] = v.z * inv;
    pT[((size_t)b * SP + t + 3) * H + h] = v.w * inv;
    if (tid == 0) p0[bh] = es0 * inv;
}

// K_y: y_part[ts][b][h][e] = sum_{t in ts-range} pT[b][t][h]*(x[b,e,t]+posA[e,t])
// LDS-transposed x; wave <-> h-quad; thread owns 8 e; no atomics, no reduction.
#define ESTR 516   // 512 + 4 pad: write bank conflicts 2-way (free), reads canonical

__global__ void __launch_bounds__(256, 2) k_y(
        const float* __restrict__ x, const float* __restrict__ posA,
        const float* __restrict__ pT, float* __restrict__ y_part) {
    int ts = blockIdx.x;          // 0..15 : 64-t range
    int eh = blockIdx.y;          // 0..1  : 512-e half
    int b  = blockIdx.z;
    int tid = threadIdx.x;
    int wave = tid >> 6, lane = tid & 63;
    int e0 = eh * 512;
    __shared__ float xs[16 * ESTR];   // 33 KB
    __shared__ float psl[16][16];
    float acc[4][8];
    #pragma unroll
    for (int j = 0; j < 4; ++j)
        #pragma unroll
        for (int i = 0; i < 8; ++i) acc[j][i] = 0.f;

    for (int ch = 0; ch < 4; ++ch) {
        int t0 = ts * 64 + ch * 16;
        __syncthreads();
        // stage 512 e x 16 t, transposed: xs[t][e]
        #pragma unroll
        for (int i = 0; i < 8; ++i) {
            int f4id = i * 256 + tid;        // 0..2047
            int row = f4id >> 2;             // 0..511
            int c4  = (f4id & 3) * 4;        // 0,4,8,12
            float4 xv = *(const float4*)(x + ((size_t)(b * E + e0 + row)) * SP + t0 + c4);
            float4 pv = *(const float4*)(posA + (size_t)(e0 + row) * SP + t0 + c4);
            xs[(c4 + 0) * ESTR + row] = xv.x + pv.x;
            xs[(c4 + 1) * ESTR + row] = xv.y + pv.y;
            xs[(c4 + 2) * ESTR + row] = xv.z + pv.z;
            xs[(c4 + 3) * ESTR + row] = xv.w + pv.w;
        }
        if (tid < 64) {
            int t = tid >> 2, hq = (tid & 3) * 4;
            float4 pv = *(const float4*)(pT + ((size_t)b * SP + t0 + t) * H + hq);
            psl[t][hq + 0] = pv.x; psl[t][hq + 1] = pv.y;
            psl[t][hq + 2] = pv.z; psl[t][hq + 3] = pv.w;
        }
        __syncthreads();
        #pragma unroll 4
        for (int t = 0; t < 16; ++t) {
            float4 xa = *(const float4*)&xs[t * ESTR + 4 * lane];
            float4 xb = *(const float4*)&xs[t * ESTR + 256 + 4 * lane];
            float4 pq = *(const float4*)&psl[t][4 * wave];
            float xch[8] = {xa.x, xa.y, xa.z, xa.w, xb.x, xb.y, xb.z, xb.w};
            float pch[4] = {pq.x, pq.y, pq.z, pq.w};
            #pragma unroll
            for (int j = 0; j < 4; ++j)
                #pragma unroll
                for (int i = 0; i < 8; ++i)
                    acc[j][i] += pch[j] * xch[i];
        }
    }
    #pragma unroll
    for (int j = 0; j < 4; ++j) {
        float* yp = y_part + (((size_t)ts * B + b) * H + 4 * wave + j) * E + e0;
        *(float4*)(yp + 4 * lane) = make_float4(acc[j][0], acc[j][1], acc[j][2], acc[j][3]);
        *(float4*)(yp + 256 + 4 * lane) = make_float4(acc[j][4], acc[j][5], acc[j][6], acc[j][7]);
    }
}

// K_yred: y[bh][e] = sum_ts y_part[ts][bh][e] + p0[bh]*x0[b][e]
__global__ void k_yred(const float* __restrict__ y_part, const float* __restrict__ p0,
                       const float* __restrict__ x0, float* __restrict__ y) {
    int bh = blockIdx.x;
    int b = bh >> 4;
    int tid = threadIdx.x;
    int e4 = tid * 4;
    float p0v = p0[bh];
    float4 xv = *(const float4*)(x0 + (size_t)b * E + e4);
    float4 s = make_float4(p0v * xv.x, p0v * xv.y, p0v * xv.z, p0v * xv.w);
    #pragma unroll
    for (int ts = 0; ts < 16; ++ts) {
        float4 v = *(const float4*)(y_part + ((size_t)ts * 256 + bh) * E + e4);
        s.x += v.x; s.y += v.y; s.z += v.z; s.w += v.w;
    }
    *(float4*)(y + (size_t)bh * E + e4) = s;
}

// K_a: a[b,c] = W_v[c,:]·y[b,h(c),:] + b_v[c]   (wave per c, 16 b at once)
__global__ void k_a(const float* __restrict__ wqkv, const float* __restrict__ bqkv,
                    const float* __restrict__ y, float* __restrict__ a) {
    int wave = threadIdx.x >> 6, lane = threadIdx.x & 63;
    int c = blockIdx.x * 4 + wave;
    int h = c >> 6;
    const float* wrow = wqkv + (size_t)(2 * E + c) * E;
    float acc[16];
    #pragma unroll
    for (int b = 0; b < 16; ++b) acc[b] = 0.f;
    #pragma unroll
    for (int it = 0; it < 4; ++it) {
        int e4 = (it * 64 + lane) * 4;
        float4 wv = *(const float4*)(wrow + e4);
        #pragma unroll
        for (int b = 0; b < 16; ++b) {
            float4 yv = *(const float4*)(y + ((size_t)(b * H + h)) * E + e4);
            acc[b] += wv.x * yv.x + wv.y * yv.y + wv.z * yv.z + wv.w * yv.w;
        }
    }
    float tot = reduce16x64(acc, lane);
    if (lane < 16) a[lane * E + c] = tot + bqkv[2 * E + c];
}

// K_out: out[b,o] = W_c[o,:]·a[b,:] + b_c[o]
__global__ void k_out(const float* __restrict__ wc, const float* __restrict__ bc,
                      const float* __restrict__ a, float* __restrict__ out) {
    int wave = threadIdx.x >> 6, lane = threadIdx.x & 63;
    int o = blockIdx.x * 4 + wave;
    const float* wrow = wc + (size_t)o * E;
    float acc[16];
    #pragma unroll
    for (int b = 0; b < 16; ++b) acc[b] = 0.f;
    #pragma unroll
    for (int it = 0; it < 4; ++it) {
        int e4 = (it * 64 + lane) * 4;
        float4 wv = *(const float4*)(wrow + e4);
        #pragma unroll
        for (int b = 0; b < 16; ++b) {
            float4 av = *(const float4*)(a + (size_t)b * E + e4);
            acc[b] += wv.x * av.x + wv.y * av.y + wv.z * av.z + wv.w * av.w;
        }
    }
    float tot = reduce16x64(acc, lane);
    if (lane < 16) out[lane * E + o] = tot + bc[o];
}

extern "C" void kernel_launch(void* const* d_in, const int* in_sizes, int n_in,
                              void* d_out, int out_size, void* d_ws, size_t ws_size,
                              hipStream_t stream) {
    const float* x    = (const float*)d_in[0];
    const float* pos  = (const float*)d_in[1];
    const float* wqkv = (const float*)d_in[2];
    const float* bqkv = (const float*)d_in[3];
    const float* wc   = (const float*)d_in[4];
    const float* bc   = (const float*)d_in[5];
    float* out = (float*)d_out;

    float* ws = (float*)d_ws;
    float* x0   = ws;                        // 16K
    float* q0   = x0 + B * E;                // 16K
    float* u    = q0 + B * E;                // 256K
    float* pT   = u + (size_t)B * H * E;     // 256K  [b][1024][16]
    float* p0   = pT + (size_t)B * SP * H;   // 256
    float* y    = p0 + B * H;                // 256K
    float* a    = y + (size_t)B * H * E;     // 16K
    float* posA = a + B * E;                 // 4M
    float* scp  = posA + (size_t)E * SP;     // 4M  (sc_part, reused as y_part)

    k_pre<<<5120, 256, 0, stream>>>(x, pos, x0, posA);
    k_q0<<<256, 256, 0, stream>>>(wqkv, bqkv, x0, q0);
    k_u<<<dim3(H, B), 256, 0, stream>>>(wqkv, q0, u);
    k_scores<<<dim3(16, B), 256, 0, stream>>>(x, posA, u, scp);
    k_softmax<<<B * H, 256, 0, stream>>>(u, x0, scp, pT, p0);
    k_y<<<dim3(16, 2, B), 256, 0, stream>>>(x, posA, pT, scp);  // scp reused as y_part
    k_yred<<<B * H, 256, 0, stream>>>(scp, p0, x0, y);
    k_a<<<256, 256, 0, stream>>>(wqkv, bqkv, y, a);
    k_out<<<256, 256, 0, stream>>>(wc, bc, a, out);
}